// Round 1
// baseline (1386.060 us; speedup 1.0000x reference)
//
#include <hip/hip_runtime.h>
#include <hip/hip_bf16.h>

typedef __attribute__((ext_vector_type(8))) short s8v;   // 8 bf16 in 4 VGPRs
typedef __attribute__((ext_vector_type(4))) float f4v;   // 4 fp32 acc

__device__ __forceinline__ void gl_lds16(const void* g, void* l) {
  __builtin_amdgcn_global_load_lds(
      (const __attribute__((address_space(1))) unsigned int*)g,
      (__attribute__((address_space(3))) unsigned int*)l, 16, 0, 0);
}

__device__ __forceinline__ unsigned short f2b(float v) {
  __hip_bfloat16 b = __float2bfloat16(v);  // RNE
  return __builtin_bit_cast(unsigned short, b);
}

// sigm(x) = 1/(1+2^(-x*log2e)) : 2 transcendental + 2 VALU (no div sequence)
__device__ __forceinline__ float sigm(float x) {
  float e = __builtin_amdgcn_exp2f(-1.442695041f * x);
  return __builtin_amdgcn_rcpf(1.0f + e);
}
// tanh(x) = 2*sigm(2x) - 1, saturates cleanly at +-1
__device__ __forceinline__ float tanh_f(float x) {
  float e = __builtin_amdgcn_exp2f(-2.885390082f * x);
  return __builtin_fmaf(2.0f, __builtin_amdgcn_rcpf(1.0f + e), -1.0f);
}

// ---------------- prep kernels ----------------

__global__ void k_conv_bf16(const float* __restrict__ src, unsigned short* __restrict__ dst, int n) {
  int i = blockIdx.x * blockDim.x + threadIdx.x;
  if (i < n) dst[i] = f2b(src[i]);
}

// W1x[n][k] = bf16(W1[n][17+k]) for k in [0,256); b1e[n] = b1[n] + W1[n][20 - slen]
__global__ void k_prep_w1(const float* __restrict__ W1, const float* __restrict__ b1,
                          const int* __restrict__ slen,
                          unsigned short* __restrict__ W1x, float* __restrict__ b1e) {
  int i = blockIdx.x * blockDim.x + threadIdx.x;
  if (i < 512 * 256) {
    int n = i >> 8, k = i & 255;
    W1x[i] = f2b(W1[n * 273 + 17 + k]);
  }
  if (i < 512) {
    int col = 20 - *slen;
    b1e[i] = b1[i] + W1[i * 273 + col];
  }
}

// Wihb = bf16(Wih); Wsum = bf16(Wih+Whh); biasg = bih+bhh; bar = 0
__global__ void k_prep_gates(const float* __restrict__ Wih, const float* __restrict__ Whh,
                             const float* __restrict__ bih, const float* __restrict__ bhh,
                             unsigned short* __restrict__ Wihb, unsigned short* __restrict__ Wsum,
                             float* __restrict__ biasg, unsigned int* __restrict__ bar) {
  int i = blockIdx.x * blockDim.x + threadIdx.x;
  if (i < 2048 * 512) {
    float a = Wih[i];
    Wihb[i] = f2b(a);
    Wsum[i] = f2b(a + Whh[i]);
  }
  if (i < 2048) biasg[i] = bih[i] + bhh[i];
  if (i == 0) *bar = 0u;
}

// ---------------- GEMM C = act(A @ Bt^T + bias), A:[M,K] bf16, Bt:[N,K] bf16 ----------------
// 128x128 tile, BK=32, 256 threads (4 waves in 2x2), 16x16x32 bf16 MFMA.
// ACT: 0 = relu, 1 = sigmoid. Output bf16.

template <int ACT>
__global__ __launch_bounds__(256)
void k_gemm_bt(const unsigned short* __restrict__ A, const unsigned short* __restrict__ Bt,
               const float* __restrict__ bias, unsigned short* __restrict__ C,
               int M, int N, int K) {
  __shared__ __align__(16) unsigned short As[128 * 32];
  __shared__ __align__(16) unsigned short Bs[128 * 32];
  const int tid = threadIdx.x;
  const int m0 = blockIdx.y * 128, n0 = blockIdx.x * 128;
  const int lane = tid & 63, wave = tid >> 6;
  const int wm = (wave >> 1) * 64, wn = (wave & 1) * 64;
  const int lr = lane & 15, lq = lane >> 4;

  f4v acc[4][4];
#pragma unroll
  for (int i = 0; i < 4; ++i)
#pragma unroll
    for (int j = 0; j < 4; ++j) acc[i][j] = (f4v){0.f, 0.f, 0.f, 0.f};

  for (int k0 = 0; k0 < K; k0 += 32) {
    __syncthreads();  // previous iter's LDS consumers done
#pragma unroll
    for (int s = 0; s < 2; ++s) {
      int cc = tid + s * 256;          // chunk index; lane-contiguous within wave
      int row = cc >> 2, kk = (cc & 3) << 3;
      gl_lds16(&A[(long)(m0 + row) * K + k0 + kk], &As[cc * 8]);
      gl_lds16(&Bt[(long)(n0 + row) * K + k0 + kk], &Bs[cc * 8]);
    }
    __syncthreads();  // drains vmcnt -> LDS valid

    s8v a[4], b[4];
#pragma unroll
    for (int i = 0; i < 4; ++i)
      a[i] = *(const s8v*)&As[(wm + i * 16 + lr) * 32 + lq * 8];
#pragma unroll
    for (int j = 0; j < 4; ++j)
      b[j] = *(const s8v*)&Bs[(wn + j * 16 + lr) * 32 + lq * 8];
#pragma unroll
    for (int i = 0; i < 4; ++i)
#pragma unroll
      for (int j = 0; j < 4; ++j)
        acc[i][j] = __builtin_amdgcn_mfma_f32_16x16x32_bf16(a[i], b[j], acc[i][j], 0, 0, 0);
  }

#pragma unroll
  for (int i = 0; i < 4; ++i) {
#pragma unroll
    for (int j = 0; j < 4; ++j) {
#pragma unroll
      for (int r = 0; r < 4; ++r) {
        int m = m0 + wm + i * 16 + lq * 4 + r;
        int n = n0 + wn + j * 16 + lr;
        float v = acc[i][j][r] + bias[n];
        v = (ACT == 0) ? fmaxf(v, 0.0f) : sigm(v);
        C[(long)m * N + n] = f2b(v);
      }
    }
  }
}

// ---------------- fallback per-step LSTM kernel (kept in case coop launch fails) ----------------

__global__ __launch_bounds__(256, 2)
void k_lstm_step(const unsigned short* __restrict__ A,   // [M,512] bf16 (h_prev or x0)
                 const unsigned short* __restrict__ Wg,  // [2048,512] bf16
                 const float* __restrict__ bias,         // [2048] = bih+bhh
                 float* __restrict__ Cst,                // [M,512] fp32 cell state
                 unsigned short* __restrict__ Hout,      // [M,512] bf16 next input
                 float* __restrict__ Out,                // [M,T,512] fp32
                 int T, int t, int first) {
  __shared__ __align__(16) unsigned short As[256 * 32];
  __shared__ __align__(16) unsigned short Bs[4 * 32 * 32];
  const int tid = threadIdx.x;
  const int m0 = blockIdx.y * 256;
  const int n0 = blockIdx.x * 32;
  const int lane = tid & 63, wave = tid >> 6;
  const int lr = lane & 15, lq = lane >> 4;
  const int wrow = wave * 64;
  const int K = 512;

  f4v acc[4][4][2];
#pragma unroll
  for (int g = 0; g < 4; ++g)
#pragma unroll
    for (int i = 0; i < 4; ++i)
#pragma unroll
      for (int j = 0; j < 2; ++j) acc[g][i][j] = (f4v){0.f, 0.f, 0.f, 0.f};

  for (int k0 = 0; k0 < K; k0 += 32) {
    __syncthreads();
#pragma unroll
    for (int s = 0; s < 4; ++s) {
      int cc = tid + s * 256;
      int row = cc >> 2, kk = (cc & 3) << 3;
      gl_lds16(&A[(long)(m0 + row) * K + k0 + kk], &As[cc * 8]);
    }
#pragma unroll
    for (int s = 0; s < 2; ++s) {
      int cc = tid + s * 256;
      int g = cc >> 7, idx = cc & 127;
      int row = idx >> 2, kk = (idx & 3) << 3;
      gl_lds16(&Wg[(long)(g * 512 + n0 + row) * K + k0 + kk], &Bs[cc * 8]);
    }
    __syncthreads();

    s8v a[4], b[4][2];
#pragma unroll
    for (int i = 0; i < 4; ++i)
      a[i] = *(const s8v*)&As[(wrow + i * 16 + lr) * 32 + lq * 8];
#pragma unroll
    for (int g = 0; g < 4; ++g)
#pragma unroll
      for (int j = 0; j < 2; ++j)
        b[g][j] = *(const s8v*)&Bs[g * 1024 + (j * 16 + lr) * 32 + lq * 8];
#pragma unroll
    for (int g = 0; g < 4; ++g)
#pragma unroll
      for (int i = 0; i < 4; ++i)
#pragma unroll
        for (int j = 0; j < 2; ++j)
          acc[g][i][j] = __builtin_amdgcn_mfma_f32_16x16x32_bf16(a[i], b[g][j], acc[g][i][j], 0, 0, 0);
  }

#pragma unroll
  for (int i = 0; i < 4; ++i) {
#pragma unroll
    for (int j = 0; j < 2; ++j) {
#pragma unroll
      for (int r = 0; r < 4; ++r) {
        int m = m0 + wrow + i * 16 + lq * 4 + r;
        int u = n0 + j * 16 + lr;
        float gi = acc[0][i][j][r] + bias[u];
        float gf = acc[1][i][j][r] + bias[512 + u];
        float gg = acc[2][i][j][r] + bias[1024 + u];
        float go = acc[3][i][j][r] + bias[1536 + u];
        float c_old = first ? 0.0f : Cst[(long)m * 512 + u];
        float cn = sigm(gf) * c_old + sigm(gi) * tanh_f(gg);
        float h = sigm(go) * tanh_f(cn);
        Cst[(long)m * 512 + u] = cn;
        Hout[(long)m * 512 + u] = f2b(h);
        __builtin_nontemporal_store(h, &Out[((long)m * T + t) * 512 + u]);
      }
    }
  }
}

// ---------------- persistent cooperative LSTM ----------------
// Grid 256 blocks x 512 threads, 1 block/CU. Block = 512 rows x (32 units x 4 gates).
// W slice resident in LDS (128 KB) for the whole kernel, XOR-swizzled (chunk ^= row&7)
// so ds_read_b128 B-fragments hit 8 distinct 16B slots (G4 pattern). A-fragments load
// global->VGPR directly (L2-resident, XCD-swizzled blockIdx). Cell state in VGPRs.
// No __syncthreads in the K-loop; steps separated by a device-scope grid barrier.

__device__ __forceinline__ void stage_W(const unsigned short* __restrict__ Wg,
                                        unsigned short* Wlds, int n0) {
  const int tid = threadIdx.x;
  const int wv = tid >> 6, ln = tid & 63;
  // 4*32*512 bf16 = 8192 chunks of 16B; 16 per thread. LDS dest linear (wave base + lane*16),
  // global source pre-inverse-swizzled so reads can use chunk ^ (row&7).
#pragma unroll
  for (int s = 0; s < 16; ++s) {
    int c = s * 512 + wv * 64 + ln;   // linear LDS chunk 0..8191
    int rf = c >> 6;                  // g*32+u, 0..127
    int c16 = c & 63;                 // chunk within row
    int g = rf >> 5, u = rf & 31;
    int src = c16 ^ (u & 7);          // inverse of read-side swizzle (involution)
    gl_lds16(&Wg[((long)(g * 512 + n0 + u)) * 512 + src * 8], &Wlds[c * 8]);
  }
  asm volatile("s_waitcnt vmcnt(0)" ::: "memory");
  __syncthreads();
}

__device__ __forceinline__ void grid_sync(unsigned int* bar, unsigned int target) {
  __syncthreads();  // drains block's vmem (stores) before release
  if (threadIdx.x == 0) {
    __threadfence();  // device-scope release: L2 writeback so other XCDs see h
    __hip_atomic_fetch_add(bar, 1u, __ATOMIC_ACQ_REL, __HIP_MEMORY_SCOPE_AGENT);
    while (__hip_atomic_load(bar, __ATOMIC_ACQUIRE, __HIP_MEMORY_SCOPE_AGENT) < target)
      __builtin_amdgcn_s_sleep(4);
    __threadfence();  // acquire: invalidate L1/L2 so fresh h is fetched
  }
  __syncthreads();
}

__global__ __launch_bounds__(512, 2)
void k_lstm_persist(const unsigned short* __restrict__ Wihb,
                    const unsigned short* __restrict__ Wsumb,
                    const float* __restrict__ biasg,
                    unsigned short* hA,   // [M,512] bf16, holds x0 at entry
                    unsigned short* hB,   // [M,512] bf16 ping-pong
                    float* __restrict__ Out,  // [M,T,512] fp32
                    unsigned int* bar, int T) {
  __shared__ __align__(16) unsigned short Wlds[4 * 32 * 512];  // 128 KB
  const int tid = threadIdx.x;
  const int wv = tid >> 6, ln = tid & 63;
  const int lr = ln & 15, lq = ln >> 4;
  const int bid = blockIdx.x;
  // XCD-aware mapping: XCD x (= bid&7 round-robin) owns m-tiles {2x, 2x+1} -> its
  // 32 blocks share 1MB of A in its own L2 across the 16 n-slices.
  const int mt = (bid & 7) * 2 + ((bid >> 3) & 1);  // 0..15
  const int nt = bid >> 4;                          // 0..15
  const int n0 = nt * 32;
  const long m0 = (long)mt * 512 + wv * 64;         // wave's row base

  float bs[4][2];
#pragma unroll
  for (int g = 0; g < 4; ++g)
#pragma unroll
    for (int j = 0; j < 2; ++j) bs[g][j] = biasg[g * 512 + n0 + j * 16 + lr];

  float cst[4][2][4];  // cell state lives here for all 16 steps
#pragma unroll
  for (int i = 0; i < 4; ++i)
#pragma unroll
    for (int j = 0; j < 2; ++j)
#pragma unroll
      for (int r = 0; r < 4; ++r) cst[i][j][r] = 0.f;

  stage_W(Wihb, Wlds, n0);  // step 0 weights (h0 = 0 -> Wih only)

  unsigned int target = gridDim.x;
  unsigned short* A = hA;
  unsigned short* H = hB;

  for (int t = 0; t < T; ++t) {
    f4v acc[4][4][2];
#pragma unroll
    for (int g = 0; g < 4; ++g)
#pragma unroll
      for (int i = 0; i < 4; ++i)
#pragma unroll
        for (int j = 0; j < 2; ++j) acc[g][i][j] = (f4v){0.f, 0.f, 0.f, 0.f};

#pragma unroll
    for (int kk = 0; kk < 16; ++kk) {
      const int k0 = kk * 32;
      s8v a[4];
#pragma unroll
      for (int i = 0; i < 4; ++i)
        a[i] = *(const s8v*)&A[(m0 + i * 16 + lr) * 512 + k0 + lq * 8];
      s8v b[4][2];
      const int cbase = k0 >> 3;
#pragma unroll
      for (int g = 0; g < 4; ++g)
#pragma unroll
        for (int j = 0; j < 2; ++j)
          b[g][j] = *(const s8v*)&Wlds[g * 16384 + (j * 16 + lr) * 512 +
                                       (((cbase + lq) ^ (lr & 7)) << 3)];
#pragma unroll
      for (int g = 0; g < 4; ++g)
#pragma unroll
        for (int i = 0; i < 4; ++i)
#pragma unroll
          for (int j = 0; j < 2; ++j)
            acc[g][i][j] =
                __builtin_amdgcn_mfma_f32_16x16x32_bf16(a[i], b[g][j], acc[g][i][j], 0, 0, 0);
    }

#pragma unroll
    for (int i = 0; i < 4; ++i) {
#pragma unroll
      for (int j = 0; j < 2; ++j) {
#pragma unroll
        for (int r = 0; r < 4; ++r) {
          long m = m0 + i * 16 + lq * 4 + r;
          int u = n0 + j * 16 + lr;
          float gi = acc[0][i][j][r] + bs[0][j];
          float gf = acc[1][i][j][r] + bs[1][j];
          float gg = acc[2][i][j][r] + bs[2][j];
          float go = acc[3][i][j][r] + bs[3][j];
          float cn = sigm(gf) * cst[i][j][r] + sigm(gi) * tanh_f(gg);
          float h = sigm(go) * tanh_f(cn);
          cst[i][j][r] = cn;
          H[m * 512 + u] = f2b(h);
          __builtin_nontemporal_store(h, &Out[(m * T + t) * 512 + u]);
        }
      }
    }

    if (t + 1 < T) {
      grid_sync(bar, target);
      target += gridDim.x;
      if (t == 0) stage_W(Wsumb, Wlds, n0);  // inp==h from now on -> Wih+Whh
      unsigned short* tmp = A; A = H; H = tmp;
    }
  }
}

// ---------------- launch ----------------

extern "C" void kernel_launch(void* const* d_in, const int* in_sizes, int n_in,
                              void* d_out, int out_size, void* d_ws, size_t ws_size,
                              hipStream_t stream) {
  const float* x   = (const float*)d_in[0];
  const float* W1  = (const float*)d_in[1];
  const float* b1  = (const float*)d_in[2];
  const float* W2  = (const float*)d_in[3];
  const float* b2  = (const float*)d_in[4];
  const float* W3  = (const float*)d_in[5];
  const float* b3  = (const float*)d_in[6];
  const float* Wih = (const float*)d_in[7];
  const float* Whh = (const float*)d_in[8];
  const float* bih = (const float*)d_in[9];
  const float* bhh = (const float*)d_in[10];
  const int* slen  = (const int*)d_in[11];
  float* out = (float*)d_out;

  const int B = in_sizes[0] / 256;     // 8192
  int T = out_size / (B * 512);        // = sentence_len = 16

  // workspace carve (256B aligned)
  size_t o = 0;
  auto alloc = [&](size_t bytes) {
    o = (o + 255) & ~(size_t)255;
    void* r = (char*)d_ws + o;
    o += bytes;
    return r;
  };
  unsigned short* xb    = (unsigned short*)alloc((size_t)B * 256 * 2);
  unsigned short* W1x   = (unsigned short*)alloc(512 * 256 * 2);
  unsigned short* W2b   = (unsigned short*)alloc(512 * 512 * 2);
  unsigned short* W3b   = (unsigned short*)alloc(512 * 512 * 2);
  unsigned short* Wihb  = (unsigned short*)alloc(2048 * 512 * 2);
  unsigned short* Wsumb = (unsigned short*)alloc(2048 * 512 * 2);
  float* b1e   = (float*)alloc(512 * 4);
  float* biasg = (float*)alloc(2048 * 4);
  unsigned short* h1 = (unsigned short*)alloc((size_t)B * 512 * 2);
  unsigned short* h2 = (unsigned short*)alloc((size_t)B * 512 * 2);
  float* cbuf = (float*)alloc((size_t)B * 512 * 4);
  unsigned int* bar = (unsigned int*)alloc(256);
  (void)ws_size;

  // prep
  k_conv_bf16<<<(B * 256 + 255) / 256, 256, 0, stream>>>(x, xb, B * 256);
  k_conv_bf16<<<(512 * 512 + 255) / 256, 256, 0, stream>>>(W2, W2b, 512 * 512);
  k_conv_bf16<<<(512 * 512 + 255) / 256, 256, 0, stream>>>(W3, W3b, 512 * 512);
  k_prep_w1<<<(512 * 256 + 255) / 256, 256, 0, stream>>>(W1, b1, slen, W1x, b1e);
  k_prep_gates<<<(2048 * 512 + 255) / 256, 256, 0, stream>>>(Wih, Whh, bih, bhh, Wihb, Wsumb,
                                                             biasg, bar);

  // MLP: h1 = relu(x@W1x^T + b1e); h2 = relu(h1@W2^T + b2); x0 = sigmoid(h2@W3^T + b3) -> h1
  k_gemm_bt<0><<<dim3(4, B / 128), 256, 0, stream>>>(xb, W1x, b1e, h1, B, 512, 256);
  k_gemm_bt<0><<<dim3(4, B / 128), 256, 0, stream>>>(h1, W2b, b2, h2, B, 512, 512);
  k_gemm_bt<1><<<dim3(4, B / 128), 256, 0, stream>>>(h2, W3b, b3, h1, B, 512, 512);

  // LSTM: persistent cooperative kernel (cell state in VGPRs, W resident in LDS).
  bool coop_ok = false;
  {
    void* kargs[] = {(void*)&Wihb, (void*)&Wsumb, (void*)&biasg, (void*)&h1,
                     (void*)&h2,   (void*)&out,   (void*)&bar,   (void*)&T};
    hipError_t e = hipLaunchCooperativeKernel((const void*)k_lstm_persist, dim3(256), dim3(512),
                                              kargs, 0, stream);
    coop_ok = (e == hipSuccess);
    if (!coop_ok) (void)hipGetLastError();  // clear sticky error, use fallback
  }

  if (!coop_ok) {
    for (int t = 0; t < T; ++t) {
      const unsigned short* a = (t % 2 == 0) ? h1 : h2;
      unsigned short* ho      = (t % 2 == 0) ? h2 : h1;
      k_lstm_step<<<dim3(512 / 32, B / 256), 256, 0, stream>>>(
          a, (t == 0) ? Wihb : Wsumb, biasg, cbuf, ho, out, T, t, (t == 0) ? 1 : 0);
    }
  }
}

// Round 2
// 741.356 us; speedup vs baseline: 1.8696x; 1.8696x over previous
//
#include <hip/hip_runtime.h>
#include <hip/hip_bf16.h>

typedef __attribute__((ext_vector_type(8))) short s8v;   // 8 bf16 in 4 VGPRs
typedef __attribute__((ext_vector_type(4))) float f4v;   // 4 fp32 acc

__device__ __forceinline__ void gl_lds16(const void* g, void* l) {
  __builtin_amdgcn_global_load_lds(
      (const __attribute__((address_space(1))) unsigned int*)g,
      (__attribute__((address_space(3))) unsigned int*)l, 16, 0, 0);
}

__device__ __forceinline__ unsigned short f2b(float v) {
  __hip_bfloat16 b = __float2bfloat16(v);  // RNE
  return __builtin_bit_cast(unsigned short, b);
}

// sigm(x) = 1/(1+2^(-x*log2e)) : 2 transcendental + 2 VALU (no div sequence)
__device__ __forceinline__ float sigm(float x) {
  float e = __builtin_amdgcn_exp2f(-1.442695041f * x);
  return __builtin_amdgcn_rcpf(1.0f + e);
}
// tanh(x) = 2*sigm(2x) - 1, saturates cleanly at +-1
__device__ __forceinline__ float tanh_f(float x) {
  float e = __builtin_amdgcn_exp2f(-2.885390082f * x);
  return __builtin_fmaf(2.0f, __builtin_amdgcn_rcpf(1.0f + e), -1.0f);
}

// ---------------- prep kernels ----------------

__global__ void k_conv_bf16(const float* __restrict__ src, unsigned short* __restrict__ dst, int n) {
  int i = blockIdx.x * blockDim.x + threadIdx.x;
  if (i < n) dst[i] = f2b(src[i]);
}

// W1x[n][k] = bf16(W1[n][17+k]) for k in [0,256); b1e[n] = b1[n] + W1[n][20 - slen]
__global__ void k_prep_w1(const float* __restrict__ W1, const float* __restrict__ b1,
                          const int* __restrict__ slen,
                          unsigned short* __restrict__ W1x, float* __restrict__ b1e) {
  int i = blockIdx.x * blockDim.x + threadIdx.x;
  if (i < 512 * 256) {
    int n = i >> 8, k = i & 255;
    W1x[i] = f2b(W1[n * 273 + 17 + k]);
  }
  if (i < 512) {
    int col = 20 - *slen;
    b1e[i] = b1[i] + W1[i * 273 + col];
  }
}

// Wihb = bf16(Wih); Wsum = bf16(Wih+Whh); biasg = bih+bhh
__global__ void k_prep_gates(const float* __restrict__ Wih, const float* __restrict__ Whh,
                             const float* __restrict__ bih, const float* __restrict__ bhh,
                             unsigned short* __restrict__ Wihb, unsigned short* __restrict__ Wsum,
                             float* __restrict__ biasg) {
  int i = blockIdx.x * blockDim.x + threadIdx.x;
  if (i < 2048 * 512) {
    float a = Wih[i];
    Wihb[i] = f2b(a);
    Wsum[i] = f2b(a + Whh[i]);
  }
  if (i < 2048) biasg[i] = bih[i] + bhh[i];
}

// ---------------- GEMM C = act(A @ Bt^T + bias), A:[M,K] bf16, Bt:[N,K] bf16 ----------------
// 128x128 tile, BK=32, 256 threads (4 waves in 2x2), 16x16x32 bf16 MFMA.
// ACT: 0 = relu, 1 = sigmoid. Output bf16.

template <int ACT>
__global__ __launch_bounds__(256)
void k_gemm_bt(const unsigned short* __restrict__ A, const unsigned short* __restrict__ Bt,
               const float* __restrict__ bias, unsigned short* __restrict__ C,
               int M, int N, int K) {
  __shared__ __align__(16) unsigned short As[128 * 32];
  __shared__ __align__(16) unsigned short Bs[128 * 32];
  const int tid = threadIdx.x;
  const int m0 = blockIdx.y * 128, n0 = blockIdx.x * 128;
  const int lane = tid & 63, wave = tid >> 6;
  const int wm = (wave >> 1) * 64, wn = (wave & 1) * 64;
  const int lr = lane & 15, lq = lane >> 4;

  f4v acc[4][4];
#pragma unroll
  for (int i = 0; i < 4; ++i)
#pragma unroll
    for (int j = 0; j < 4; ++j) acc[i][j] = (f4v){0.f, 0.f, 0.f, 0.f};

  for (int k0 = 0; k0 < K; k0 += 32) {
    __syncthreads();  // previous iter's LDS consumers done
#pragma unroll
    for (int s = 0; s < 2; ++s) {
      int cc = tid + s * 256;          // chunk index; lane-contiguous within wave
      int row = cc >> 2, kk = (cc & 3) << 3;
      gl_lds16(&A[(long)(m0 + row) * K + k0 + kk], &As[cc * 8]);
      gl_lds16(&Bt[(long)(n0 + row) * K + k0 + kk], &Bs[cc * 8]);
    }
    __syncthreads();  // drains vmcnt -> LDS valid

    s8v a[4], b[4];
#pragma unroll
    for (int i = 0; i < 4; ++i)
      a[i] = *(const s8v*)&As[(wm + i * 16 + lr) * 32 + lq * 8];
#pragma unroll
    for (int j = 0; j < 4; ++j)
      b[j] = *(const s8v*)&Bs[(wn + j * 16 + lr) * 32 + lq * 8];
#pragma unroll
    for (int i = 0; i < 4; ++i)
#pragma unroll
      for (int j = 0; j < 4; ++j)
        acc[i][j] = __builtin_amdgcn_mfma_f32_16x16x32_bf16(a[i], b[j], acc[i][j], 0, 0, 0);
  }

#pragma unroll
  for (int i = 0; i < 4; ++i) {
#pragma unroll
    for (int j = 0; j < 4; ++j) {
#pragma unroll
      for (int r = 0; r < 4; ++r) {
        int m = m0 + wm + i * 16 + lq * 4 + r;
        int n = n0 + wn + j * 16 + lr;
        float v = acc[i][j][r] + bias[n];
        v = (ACT == 0) ? fmaxf(v, 0.0f) : sigm(v);
        C[(long)m * N + n] = f2b(v);
      }
    }
  }
}

// ---------------- LSTM step v2 ----------------
// Tile: 128 rows x 32 units (x4 gates). Grid 1024 blocks x 256 threads = 4 blocks/CU.
// XCD-co-located mapping: all 16 n-blocks of an m-tile share bid%8 -> same XCD ->
// A (prev H) and W stay L2-hot per XCD across steps (W is identical every step).
// 2-phase pipeline: double-buffered LDS, stage tile kt+1 issued BEFORE compute of kt,
// ONE barrier per K-tile (syncthreads drains vmcnt+lgkmcnt).
// Per wave: 64 rows x 16 units x 4 gates; acc[4][4] f4v = 64 VGPR.

__global__ __launch_bounds__(256, 4)
void k_lstm_step2(const unsigned short* __restrict__ A,   // [M,512] bf16 (h_prev or x0)
                  const unsigned short* __restrict__ Wg,  // [2048,512] bf16
                  const float* __restrict__ bias,         // [2048] = bih+bhh
                  float* __restrict__ Cst,                // [M,512] fp32 cell state
                  unsigned short* __restrict__ Hout,      // [M,512] bf16 next input
                  float* __restrict__ Out,                // [M,T,512] fp32
                  int T, int t, int first) {
  __shared__ __align__(16) unsigned short As[2][128 * 32];   // 2 x 8 KB
  __shared__ __align__(16) unsigned short Bs[2][4 * 32 * 32];  // 2 x 8 KB
  const int tid = threadIdx.x;
  // XCD swizzle: p%8 = XCD; mt = (p&7) + 8*((p>>3)&7) in [0,64); nt = p>>6 in [0,16).
  const int p = blockIdx.x;
  const int q = p >> 3;
  const int mt = (p & 7) + ((q & 7) << 3);
  const int nt = q >> 3;
  const long m0 = (long)mt * 128;
  const int n0 = nt * 32;
  const int lane = tid & 63, wave = tid >> 6;
  const int lr = lane & 15, lq = lane >> 4;
  const int wr = (wave >> 1) * 64;   // wave row base (0 or 64)
  const int wu = (wave & 1) * 16;    // wave unit base (0 or 16)

  f4v acc[4][4];  // [gate][m-frag]
#pragma unroll
  for (int g = 0; g < 4; ++g)
#pragma unroll
    for (int i = 0; i < 4; ++i) acc[g][i] = (f4v){0.f, 0.f, 0.f, 0.f};

  // ---- staging: A tile 128x32 = 512 chunks(16B); B tile 4x32x32 = 512 chunks ----
  auto stage = [&](int sel, int kt) {
#pragma unroll
    for (int s = 0; s < 2; ++s) {
      int c = tid + s * 256;                  // A chunk 0..511
      int row = c >> 2, kk = (c & 3) << 3;
      gl_lds16(&A[(m0 + row) * 512 + kt * 32 + kk], &As[sel][c * 8]);
    }
#pragma unroll
    for (int s = 0; s < 2; ++s) {
      int c = tid + s * 256;                  // B chunk 0..511
      int g = c >> 7, idx = c & 127;
      int row = idx >> 2, kk = (idx & 3) << 3;
      gl_lds16(&Wg[((long)(g * 512 + n0 + row)) * 512 + kt * 32 + kk], &Bs[sel][c * 8]);
    }
  };

  stage(0, 0);
  __syncthreads();  // drains vmcnt(0): tile 0 valid

  int sel = 0;
  for (int kt = 0; kt < 16; ++kt) {
    if (kt < 15) stage(sel ^ 1, kt + 1);  // issue next-tile DMA before compute

    s8v a[4], b[4];
#pragma unroll
    for (int i = 0; i < 4; ++i)
      a[i] = *(const s8v*)&As[sel][(wr + i * 16 + lr) * 32 + lq * 8];
#pragma unroll
    for (int g = 0; g < 4; ++g)
      b[g] = *(const s8v*)&Bs[sel][g * 1024 + (wu + lr) * 32 + lq * 8];
#pragma unroll
    for (int g = 0; g < 4; ++g)
#pragma unroll
      for (int i = 0; i < 4; ++i)
        acc[g][i] = __builtin_amdgcn_mfma_f32_16x16x32_bf16(a[i], b[g], acc[g][i], 0, 0, 0);

    if (kt < 15) {
      __syncthreads();  // one barrier per tile: drains vmcnt (next tile ready)
      sel ^= 1;
    }
  }

  // ---- fused cell epilogue ----
#pragma unroll
  for (int i = 0; i < 4; ++i) {
#pragma unroll
    for (int r = 0; r < 4; ++r) {
      long m = m0 + wr + i * 16 + lq * 4 + r;
      int u = n0 + wu + lr;
      float gi = acc[0][i][r] + bias[u];
      float gf = acc[1][i][r] + bias[512 + u];
      float gg = acc[2][i][r] + bias[1024 + u];
      float go = acc[3][i][r] + bias[1536 + u];
      float c_old = first ? 0.0f : Cst[m * 512 + u];
      float cn = sigm(gf) * c_old + sigm(gi) * tanh_f(gg);
      float h = sigm(go) * tanh_f(cn);
      Cst[m * 512 + u] = cn;
      Hout[m * 512 + u] = f2b(h);
      __builtin_nontemporal_store(h, &Out[(m * T + t) * 512 + u]);
    }
  }
}

// ---------------- launch ----------------

extern "C" void kernel_launch(void* const* d_in, const int* in_sizes, int n_in,
                              void* d_out, int out_size, void* d_ws, size_t ws_size,
                              hipStream_t stream) {
  const float* x   = (const float*)d_in[0];
  const float* W1  = (const float*)d_in[1];
  const float* b1  = (const float*)d_in[2];
  const float* W2  = (const float*)d_in[3];
  const float* b2  = (const float*)d_in[4];
  const float* W3  = (const float*)d_in[5];
  const float* b3  = (const float*)d_in[6];
  const float* Wih = (const float*)d_in[7];
  const float* Whh = (const float*)d_in[8];
  const float* bih = (const float*)d_in[9];
  const float* bhh = (const float*)d_in[10];
  const int* slen  = (const int*)d_in[11];
  float* out = (float*)d_out;

  const int B = in_sizes[0] / 256;     // 8192
  const int T = out_size / (B * 512);  // = sentence_len = 16

  // workspace carve (256B aligned)
  size_t o = 0;
  auto alloc = [&](size_t bytes) {
    o = (o + 255) & ~(size_t)255;
    void* r = (char*)d_ws + o;
    o += bytes;
    return r;
  };
  unsigned short* xb    = (unsigned short*)alloc((size_t)B * 256 * 2);
  unsigned short* W1x   = (unsigned short*)alloc(512 * 256 * 2);
  unsigned short* W2b   = (unsigned short*)alloc(512 * 512 * 2);
  unsigned short* W3b   = (unsigned short*)alloc(512 * 512 * 2);
  unsigned short* Wihb  = (unsigned short*)alloc(2048 * 512 * 2);
  unsigned short* Wsumb = (unsigned short*)alloc(2048 * 512 * 2);
  float* b1e   = (float*)alloc(512 * 4);
  float* biasg = (float*)alloc(2048 * 4);
  unsigned short* h1 = (unsigned short*)alloc((size_t)B * 512 * 2);
  unsigned short* h2 = (unsigned short*)alloc((size_t)B * 512 * 2);
  float* cbuf = (float*)alloc((size_t)B * 512 * 4);
  (void)ws_size;

  // prep
  k_conv_bf16<<<(B * 256 + 255) / 256, 256, 0, stream>>>(x, xb, B * 256);
  k_conv_bf16<<<(512 * 512 + 255) / 256, 256, 0, stream>>>(W2, W2b, 512 * 512);
  k_conv_bf16<<<(512 * 512 + 255) / 256, 256, 0, stream>>>(W3, W3b, 512 * 512);
  k_prep_w1<<<(512 * 256 + 255) / 256, 256, 0, stream>>>(W1, b1, slen, W1x, b1e);
  k_prep_gates<<<(2048 * 512 + 255) / 256, 256, 0, stream>>>(Wih, Whh, bih, bhh, Wihb, Wsumb,
                                                             biasg);

  // MLP: h1 = relu(x@W1x^T + b1e); h2 = relu(h1@W2^T + b2); x0 = sigmoid(h2@W3^T + b3) -> h1
  k_gemm_bt<0><<<dim3(4, B / 128), 256, 0, stream>>>(xb, W1x, b1e, h1, B, 512, 256);
  k_gemm_bt<0><<<dim3(4, B / 128), 256, 0, stream>>>(h1, W2b, b2, h2, B, 512, 512);
  k_gemm_bt<1><<<dim3(4, B / 128), 256, 0, stream>>>(h2, W3b, b3, h1, B, 512, 512);

  // LSTM: step 0 uses Wih only (h0=0, c0=0); steps >=1 use Wih+Whh since inp==h.
  for (int t = 0; t < T; ++t) {
    const unsigned short* a = (t % 2 == 0) ? h1 : h2;
    unsigned short* ho      = (t % 2 == 0) ? h2 : h1;
    k_lstm_step2<<<dim3(1024), 256, 0, stream>>>(
        a, (t == 0) ? Wihb : Wsumb, biasg, cbuf, ho, out, T, t, (t == 0) ? 1 : 0);
  }
}